// Round 1
// 185.544 us; speedup vs baseline: 1.0363x; 1.0363x over previous
//
#include <hip/hip_runtime.h>

#define NB 16384
#define NC 1000
#define NF 256

typedef _Float16 half8 __attribute__((ext_vector_type(8)));
typedef float f32x4 __attribute__((ext_vector_type(4)));

// ---- prep: fragment-ordered fp16 means + SoA per-class params ----
// m16f layout: [gt 0..63][kk 0..7][slot 0..63] half8 units where
//   slot s of (gt,kk) = means[min(gt*16+(s&15),999)][kk*32+(s>>4)*8 .. +8]
// This matches the mfma_f32_16x16x32_f16 A-operand lane layout exactly, so
// score's per-(tile,kk) means load is ONE coalesced 1024B dwordx4 per wave.
__global__ __launch_bounds__(256) void prep_kernel(
    const float* __restrict__ mean_vecs,
    const float* __restrict__ wb_shape,
    const float* __restrict__ wb_loc,
    const float* __restrict__ wb_scale,
    _Float16* __restrict__ m16f,
    float* __restrict__ pm2,
    float* __restrict__ psh,
    float* __restrict__ pli,
    float* __restrict__ pis)
{
    const int lane = threadIdx.x & 63;
    const int W = blockIdx.x * 4 + (threadIdx.x >> 6);   // grid=252 -> W in [0,1008)

    if (W < 512) {                                       // fragment-order means
        const int gt = W >> 3, kk = W & 7;
        int cls = gt * 16 + (lane & 15);
        if (cls > NC - 1) cls = NC - 1;                  // clamp tail slots
        const float* src = mean_vecs + (size_t)cls * NF + kk * 32 + (lane >> 4) * 8;
        const float4 lo = *(const float4*)src;
        const float4 hi = *(const float4*)(src + 4);
        half8 h;
        h[0]=(_Float16)lo.x; h[1]=(_Float16)lo.y; h[2]=(_Float16)lo.z; h[3]=(_Float16)lo.w;
        h[4]=(_Float16)hi.x; h[5]=(_Float16)hi.y; h[6]=(_Float16)hi.z; h[7]=(_Float16)hi.w;
        *((half8*)m16f + (size_t)W * 64 + lane) = h;     // coalesced 1024B per wave
    }
    if (W < NC) {                                        // per-class params, exact fp32 m2
        const float4 v = *((const float4*)(mean_vecs + (size_t)W * NF) + lane);
        float s = v.x*v.x + v.y*v.y + v.z*v.z + v.w*v.w;
        #pragma unroll
        for (int off = 1; off < 64; off <<= 1) s += __shfl_xor(s, off, 64);
        if (lane == 0) {
            const float isc = 1.0f / wb_scale[W];
            pm2[W] = s;
            psh[W] = wb_shape[W];
            pli[W] = wb_loc[W] * isc;                    // loc/scale
            pis[W] = isc;
        }
    }
}

// ---- single-pass score: 16 rows x all 1000 classes per block ----
// 8 waves; wave w owns class tiles [w*8, w*8+8) (128 classes) of the SAME 16
// rows. e-values live in 32 VGPRs/thread; the row-sum is completed in-block
// (shfl + tiny LDS), so output is written normalized ONCE. No norm pass, no
// partial buffer, no main-loop barriers, no LDS staging.
__global__ __launch_bounds__(512, 4) void score_kernel(
    const float* __restrict__ logits,
    const float* __restrict__ features,
    const _Float16* __restrict__ m16f,
    const float* __restrict__ pm2,
    const float* __restrict__ psh,
    const float* __restrict__ pli,
    const float* __restrict__ pis,
    float* __restrict__ out)
{
    __shared__ float ssum[8][16];                        // 512 B total LDS

    const int lane = threadIdx.x & 63;
    const int wave = threadIdx.x >> 6;
    const int q    = lane >> 4;                          // class sub-group (4 classes)
    const int mr   = lane & 15;                          // row within block's 16-row tile
    const int row  = blockIdx.x * 16 + mr;

    // ---- B fragments (features for this lane's row) + exact-fp32 f2 ----
    half8 bfrag[8];
    float f2 = 0.f;
    const float* fb = features + (size_t)row * NF;
    #pragma unroll
    for (int kk = 0; kk < 8; ++kk) {
        const float4* p = (const float4*)(fb + kk * 32 + q * 8);
        const float4 lo = p[0], hi = p[1];
        f2 += lo.x*lo.x + lo.y*lo.y + lo.z*lo.z + lo.w*lo.w
            + hi.x*hi.x + hi.y*hi.y + hi.z*hi.z + hi.w*hi.w;
        half8 b;
        b[0]=(_Float16)lo.x; b[1]=(_Float16)lo.y; b[2]=(_Float16)lo.z; b[3]=(_Float16)lo.w;
        b[4]=(_Float16)hi.x; b[5]=(_Float16)hi.y; b[6]=(_Float16)hi.z; b[7]=(_Float16)hi.w;
        bfrag[kk] = b;
    }
    f2 += __shfl_xor(f2, 16, 64);                        // sum the 4 q-chunks (same row)
    f2 += __shfl_xor(f2, 32, 64);

    const float LOG2E = 1.44269504088896340736f;
    float rsum = 0.f;
    f32x4 ev[8];                                         // unnormalized exp, 32 VGPRs

    const half8* mbase = (const half8*)m16f + (size_t)(wave * 8) * 8 * 64 + lane;

    #pragma unroll
    for (int t = 0; t < 8; ++t) {
        const int gt  = wave * 8 + t;                    // global class tile 0..63
        const int cb  = gt * 16 + q * 4;
        const bool cvg = (cb <= NC - 4);                 // all-4-or-none lane validity
        const int cbc = cvg ? cb : (NC - 4);             // clamped, 16B aligned

        // A fragments: one coalesced 1024B L2 load per kk (fragment-order buffer)
        half8 a[8];
        #pragma unroll
        for (int kk = 0; kk < 8; ++kk)
            a[kk] = mbase[(size_t)(t * 8 + kk) * 64];

        f32x4 acc = {0.f, 0.f, 0.f, 0.f};
        #pragma unroll
        for (int kk = 0; kk < 8; ++kk)
            acc = __builtin_amdgcn_mfma_f32_16x16x32_f16(a[kk], bfrag[kk], acc, 0, 0, 0);

        const float4 lg  = *(const float4*)(logits + (size_t)row * NC + cbc);
        const float4 m2v = *(const float4*)(pm2 + cbc);
        const float4 shv = *(const float4*)(psh + cbc);
        const float4 liv = *(const float4*)(pli + cbc);
        const float4 iv  = *(const float4*)(pis + cbc);

        const float* m2a = (const float*)&m2v;
        const float* sha = (const float*)&shv;
        const float* lia = (const float*)&liv;
        const float* iva = (const float*)&iv;
        const float* lga = (const float*)&lg;

        #pragma unroll
        for (int j = 0; j < 4; ++j) {
            float d2   = fmaxf(f2 + m2a[j] - 2.0f * acc[j], 1e-12f);
            float dist = sqrtf(d2);
            float xp   = dist * iva[j] - lia[j];         // (dist-loc)/scale
            float xs   = fmaxf(xp, 1e-30f);
            float tt   = exp2f(sha[j] * log2f(xs));      // xp^shape
            float w    = 1.0f - exp2f(-LOG2E * tt);      // weibull CDF
            w = (xp > 0.f) ? w : 0.f;
            float w2 = w * w, w4 = w2 * w2, w8 = w4 * w4;
            float s  = lga[j] * (1.0f - w8 * w2);        // logit*(1-w^10)
            float e  = exp2f(LOG2E * s);                 // exp(s)
            e = cvg ? e : 0.f;
            rsum += e;
            ev[t][j] = e;
        }
    }

    // ---- complete the row softmax denominator in-block ----
    rsum += __shfl_xor(rsum, 16, 64);                    // across 4 q-groups
    rsum += __shfl_xor(rsum, 32, 64);
    if (lane < 16) ssum[wave][lane] = rsum;              // per-wave 128-class sums
    __syncthreads();
    float tot = 0.f;
    #pragma unroll
    for (int w = 0; w < 8; ++w) tot += ssum[w][mr];
    const float inv = 1.0f / tot;

    // ---- normalized write, once ----
    #pragma unroll
    for (int t = 0; t < 8; ++t) {
        const int gt = wave * 8 + t;
        const int cb = gt * 16 + q * 4;
        if (cb <= NC - 4) {
            float4 o;
            o.x = ev[t][0] * inv; o.y = ev[t][1] * inv;
            o.z = ev[t][2] * inv; o.w = ev[t][3] * inv;
            *(float4*)(out + (size_t)row * NC + cb) = o;
        }
    }
}

extern "C" void kernel_launch(void* const* d_in, const int* in_sizes, int n_in,
                              void* d_out, int out_size, void* d_ws, size_t ws_size,
                              hipStream_t stream) {
    const float* logits    = (const float*)d_in[0];
    const float* features  = (const float*)d_in[1];
    const float* mean_vecs = (const float*)d_in[2];
    const float* wb_shape  = (const float*)d_in[3];
    const float* wb_loc    = (const float*)d_in[4];
    const float* wb_scale  = (const float*)d_in[5];
    float* out = (float*)d_out;

    // ws layout: m16f 524288 B | pm2 4096 | psh 4096 | pli 4096 | pis 4096
    _Float16* m16f = (_Float16*)d_ws;
    float* pm2 = (float*)((char*)d_ws + 524288);
    float* psh = (float*)((char*)d_ws + 524288 + 4096);
    float* pli = (float*)((char*)d_ws + 524288 + 8192);
    float* pis = (float*)((char*)d_ws + 524288 + 12288);

    prep_kernel<<<252, 256, 0, stream>>>(mean_vecs, wb_shape, wb_loc, wb_scale,
                                         m16f, pm2, psh, pli, pis);
    score_kernel<<<NB / 16, 512, 0, stream>>>(logits, features, m16f,
                                              pm2, psh, pli, pis, out);
}

// Round 3
// 183.731 us; speedup vs baseline: 1.0465x; 1.0099x over previous
//
#include <hip/hip_runtime.h>

#define NB 16384
#define NC 1000
#define NF 256
#define SE_STRIDE 1004   // floats per e-row in LDS (1000 + pad, 16B-aligned)

typedef _Float16 half8 __attribute__((ext_vector_type(8)));
typedef float f32x4 __attribute__((ext_vector_type(4)));

// ---- prep: fragment-ordered fp16 means + SoA per-class params ----
// m16f layout: [gt 0..63][kk 0..7][slot 0..63] half8 units where
//   slot s of (gt,kk) = means[min(gt*16+(s&15),999)][kk*32+(s>>4)*8 .. +8]
// Matches the mfma_f32_16x16x32_f16 A-operand lane layout exactly: score's
// per-(tile,kk) means load is ONE coalesced 1024B dwordx4 per wave.
__global__ __launch_bounds__(256) void prep_kernel(
    const float* __restrict__ mean_vecs,
    const float* __restrict__ wb_shape,
    const float* __restrict__ wb_loc,
    const float* __restrict__ wb_scale,
    _Float16* __restrict__ m16f,
    float* __restrict__ pm2,
    float* __restrict__ psh,
    float* __restrict__ pli,
    float* __restrict__ pis)
{
    const int lane = threadIdx.x & 63;
    const int W = blockIdx.x * 4 + (threadIdx.x >> 6);   // grid=252 -> W in [0,1008)

    if (W < 512) {                                       // fragment-order means
        const int gt = W >> 3, kk = W & 7;
        int cls = gt * 16 + (lane & 15);
        if (cls > NC - 1) cls = NC - 1;                  // clamp tail slots
        const float* src = mean_vecs + (size_t)cls * NF + kk * 32 + (lane >> 4) * 8;
        const float4 lo = *(const float4*)src;
        const float4 hi = *(const float4*)(src + 4);
        half8 h;
        h[0]=(_Float16)lo.x; h[1]=(_Float16)lo.y; h[2]=(_Float16)lo.z; h[3]=(_Float16)lo.w;
        h[4]=(_Float16)hi.x; h[5]=(_Float16)hi.y; h[6]=(_Float16)hi.z; h[7]=(_Float16)hi.w;
        *((half8*)m16f + (size_t)W * 64 + lane) = h;     // coalesced 1024B per wave
    }
    if (W < NC) {                                        // per-class params, exact fp32 m2
        const float4 v = *((const float4*)(mean_vecs + (size_t)W * NF) + lane);
        float s = v.x*v.x + v.y*v.y + v.z*v.z + v.w*v.w;
        #pragma unroll
        for (int off = 1; off < 64; off <<= 1) s += __shfl_xor(s, off, 64);
        if (lane == 0) {
            const float isc = 1.0f / wb_scale[W];
            pm2[W] = s;
            psh[W] = wb_shape[W];
            pli[W] = wb_loc[W] * isc;                    // loc/scale
            pis[W] = isc;
        }
    }
}

// ---- single-pass score: 16 rows x all 1000 classes per block ----
// 8 waves; wave w owns class tiles [w*8, w*8+8). e-values go to a 64KB LDS
// buffer (frees 32 VGPRs vs register-resident ev), A-fragments are software-
// pipelined one tile deep (issue t+1 loads under t's Weibull math). Row
// softmax denominator completed in-block; output written normalized ONCE.
__global__ __launch_bounds__(512, 4) void score_kernel(
    const float* __restrict__ logits,
    const float* __restrict__ features,
    const _Float16* __restrict__ m16f,
    const float* __restrict__ pm2,
    const float* __restrict__ psh,
    const float* __restrict__ pli,
    const float* __restrict__ pis,
    float* __restrict__ out)
{
    __shared__ float se[16][SE_STRIDE];                  // 64256 B unnormalized e
    __shared__ float ssum[8][16];
    __shared__ float sinv[16];

    const int lane = threadIdx.x & 63;
    const int wave = threadIdx.x >> 6;
    const int q    = lane >> 4;                          // class sub-group (4 classes)
    const int mr   = lane & 15;                          // row within block's 16-row tile
    const int row  = blockIdx.x * 16 + mr;

    // ---- B fragments (features for this lane's row) + exact-fp32 f2 ----
    half8 bfrag[8];
    float f2 = 0.f;
    const float* fb = features + (size_t)row * NF;
    #pragma unroll
    for (int kk = 0; kk < 8; ++kk) {
        const float4* p = (const float4*)(fb + kk * 32 + q * 8);
        const float4 lo = p[0], hi = p[1];
        f2 += lo.x*lo.x + lo.y*lo.y + lo.z*lo.z + lo.w*lo.w
            + hi.x*hi.x + hi.y*hi.y + hi.z*hi.z + hi.w*hi.w;
        half8 b;
        b[0]=(_Float16)lo.x; b[1]=(_Float16)lo.y; b[2]=(_Float16)lo.z; b[3]=(_Float16)lo.w;
        b[4]=(_Float16)hi.x; b[5]=(_Float16)hi.y; b[6]=(_Float16)hi.z; b[7]=(_Float16)hi.w;
        bfrag[kk] = b;
    }
    f2 += __shfl_xor(f2, 16, 64);                        // sum the 4 q-chunks (same row)
    f2 += __shfl_xor(f2, 32, 64);

    const float LOG2E = 1.44269504088896340736f;
    float rsum = 0.f;

    const half8* mbase = (const half8*)m16f + (size_t)(wave * 8) * 8 * 64 + lane;
    const float* lrow  = logits + (size_t)row * NC;

    // ---- prefetch tile 0 (A-fragments + logits) ----
    half8 a[8];
    #pragma unroll
    for (int kk = 0; kk < 8; ++kk)
        a[kk] = mbase[kk * 64];
    float4 lg = *(const float4*)(lrow + (wave * 128 + q * 4));   // always in-range

    #pragma unroll
    for (int t = 0; t < 8; ++t) {
        const int gt   = wave * 8 + t;                   // global class tile 0..63
        const int cb   = gt * 16 + q * 4;
        const bool cvg = (cb <= NC - 4);                 // all-4-or-none lane validity
        const int cbc  = cvg ? cb : (NC - 4);            // clamped, 16B aligned

        // ---- MFMA on prefetched tile t ----
        f32x4 acc = {0.f, 0.f, 0.f, 0.f};
        #pragma unroll
        for (int kk = 0; kk < 8; ++kk)
            acc = __builtin_amdgcn_mfma_f32_16x16x32_f16(a[kk], bfrag[kk], acc, 0, 0, 0);

        // ---- issue tile t+1 loads; Weibull below covers the L2 latency ----
        float4 lgn = lg;
        if (t < 7) {
            #pragma unroll
            for (int kk = 0; kk < 8; ++kk)
                a[kk] = mbase[(size_t)((t + 1) * 8 + kk) * 64];
            const int cbn  = cb + 16;
            const int cbnc = (cbn <= NC - 4) ? cbn : (NC - 4);
            lgn = *(const float4*)(lrow + cbnc);
        }

        // ---- per-class params (16KB arrays, cache-hot across all blocks) ----
        const float4 m2v = *(const float4*)(pm2 + cbc);
        const float4 shv = *(const float4*)(psh + cbc);
        const float4 liv = *(const float4*)(pli + cbc);
        const float4 iv  = *(const float4*)(pis + cbc);

        const float* m2a = (const float*)&m2v;
        const float* sha = (const float*)&shv;
        const float* lia = (const float*)&liv;
        const float* iva = (const float*)&iv;
        const float* lga = (const float*)&lg;

        f32x4 o;
        #pragma unroll
        for (int j = 0; j < 4; ++j) {
            float d2   = fmaxf(f2 + m2a[j] - 2.0f * acc[j], 1e-12f);
            float dist = sqrtf(d2);
            float xp   = dist * iva[j] - lia[j];         // (dist-loc)/scale
            float xs   = fmaxf(xp, 1e-30f);
            float tt   = exp2f(sha[j] * log2f(xs));      // xp^shape
            float w    = 1.0f - exp2f(-LOG2E * tt);      // weibull CDF
            w = (xp > 0.f) ? w : 0.f;
            float w2 = w * w, w4 = w2 * w2, w8 = w4 * w4;
            float s  = lga[j] * (1.0f - w8 * w2);        // logit*(1-w^10)
            float e  = exp2f(LOG2E * s);                 // exp(s)
            e = cvg ? e : 0.f;                           // MASK tail: keeps rsum exact
            rsum += e;
            o[j] = e;
        }

        if (cvg)
            *(f32x4*)&se[mr][cb] = o;                    // e row-buffer in LDS

        lg = lgn;
    }

    // ---- complete the row softmax denominator in-block ----
    rsum += __shfl_xor(rsum, 16, 64);                    // across 4 q-groups
    rsum += __shfl_xor(rsum, 32, 64);
    if (lane < 16) ssum[wave][lane] = rsum;              // per-wave 128-class sums
    __syncthreads();                                     // ssum + all se writes visible
    if (wave == 0 && lane < 16) {
        float tot = 0.f;
        #pragma unroll
        for (int w = 0; w < 8; ++w) tot += ssum[w][lane];
        sinv[lane] = 1.0f / tot;
    }
    __syncthreads();                                     // sinv ready

    // ---- phase 2: normalized write, contiguous full-BW LDS reads ----
    #pragma unroll
    for (int rr = 0; rr < 2; ++rr) {
        const int r = wave * 2 + rr;
        const float inv = sinv[r];
        float* orow = out + (size_t)(blockIdx.x * 16 + r) * NC;
        #pragma unroll
        for (int i = 0; i < 4; ++i) {
            const int idx = i * 64 + lane;               // float4 index within row
            if (idx < 250) {
                float4 v = *(const float4*)&se[r][idx * 4];
                v.x *= inv; v.y *= inv; v.z *= inv; v.w *= inv;
                *(float4*)(orow + idx * 4) = v;
            }
        }
    }
}

extern "C" void kernel_launch(void* const* d_in, const int* in_sizes, int n_in,
                              void* d_out, int out_size, void* d_ws, size_t ws_size,
                              hipStream_t stream) {
    const float* logits    = (const float*)d_in[0];
    const float* features  = (const float*)d_in[1];
    const float* mean_vecs = (const float*)d_in[2];
    const float* wb_shape  = (const float*)d_in[3];
    const float* wb_loc    = (const float*)d_in[4];
    const float* wb_scale  = (const float*)d_in[5];
    float* out = (float*)d_out;

    // ws layout: m16f 524288 B | pm2 4096 | psh 4096 | pli 4096 | pis 4096
    _Float16* m16f = (_Float16*)d_ws;
    float* pm2 = (float*)((char*)d_ws + 524288);
    float* psh = (float*)((char*)d_ws + 524288 + 4096);
    float* pli = (float*)((char*)d_ws + 524288 + 8192);
    float* pis = (float*)((char*)d_ws + 524288 + 12288);

    prep_kernel<<<252, 256, 0, stream>>>(mean_vecs, wb_shape, wb_loc, wb_scale,
                                         m16f, pm2, psh, pli, pis);
    score_kernel<<<NB / 16, 512, 0, stream>>>(logits, features, m16f,
                                              pm2, psh, pli, pis, out);
}

// Round 4
// 170.831 us; speedup vs baseline: 1.1256x; 1.0755x over previous
//
#include <hip/hip_runtime.h>

#define NB 16384
#define NC 1000
#define NF 256
#define SE_STRIDE 1004   // floats per g-row in LDS (1000 + pad, 16B-aligned)

typedef _Float16 half8 __attribute__((ext_vector_type(8)));
typedef float f32x4 __attribute__((ext_vector_type(4)));

// ---- prep: fragment-ordered fp16 means + SoA per-class params ----
// m16f layout: [gt 0..63][kk 0..7][slot 0..63] half8 units where
//   slot s of (gt,kk) = means[min(gt*16+(s&15),999)][kk*32+(s>>4)*8 .. +8]
// Matches the mfma_f32_16x16x32_f16 A-operand lane layout exactly: score's
// per-(tile,kk) means load is ONE coalesced 1024B dwordx4 per wave.
__global__ __launch_bounds__(256) void prep_kernel(
    const float* __restrict__ mean_vecs,
    const float* __restrict__ wb_shape,
    const float* __restrict__ wb_loc,
    const float* __restrict__ wb_scale,
    _Float16* __restrict__ m16f,
    float* __restrict__ pm2,
    float* __restrict__ psh,
    float* __restrict__ pli,
    float* __restrict__ pis)
{
    const int lane = threadIdx.x & 63;
    const int W = blockIdx.x * 4 + (threadIdx.x >> 6);   // grid=252 -> W in [0,1008)

    if (W < 512) {                                       // fragment-order means
        const int gt = W >> 3, kk = W & 7;
        int cls = gt * 16 + (lane & 15);
        if (cls > NC - 1) cls = NC - 1;                  // clamp tail slots
        const float* src = mean_vecs + (size_t)cls * NF + kk * 32 + (lane >> 4) * 8;
        const float4 lo = *(const float4*)src;
        const float4 hi = *(const float4*)(src + 4);
        half8 h;
        h[0]=(_Float16)lo.x; h[1]=(_Float16)lo.y; h[2]=(_Float16)lo.z; h[3]=(_Float16)lo.w;
        h[4]=(_Float16)hi.x; h[5]=(_Float16)hi.y; h[6]=(_Float16)hi.z; h[7]=(_Float16)hi.w;
        *((half8*)m16f + (size_t)W * 64 + lane) = h;     // coalesced 1024B per wave
    }
    if (W < NC) {                                        // per-class params, exact fp32 m2
        const float4 v = *((const float4*)(mean_vecs + (size_t)W * NF) + lane);
        float s = v.x*v.x + v.y*v.y + v.z*v.z + v.w*v.w;
        #pragma unroll
        for (int off = 1; off < 64; off <<= 1) s += __shfl_xor(s, off, 64);
        if (lane == 0) {
            const float isc = 1.0f / wb_scale[W];
            pm2[W] = s;
            psh[W] = wb_shape[W];
            pli[W] = wb_loc[W] * isc;                    // loc/scale
            pis[W] = isc;
        }
    }
}

// ---- single-pass score: 16 rows x all 1000 classes per block ----
// Main loop is logits-free: it computes g = 1 - w^10 (distance-only) into a
// 64KB LDS buffer in MFMA fragment layout. Per-tile load stream = means
// (coalesced 1024B, L2-resident, prefetched 1 deep) + params (L1 broadcast).
// Phase 2: each wave owns 2 full rows -- reads g from LDS and logits
// COALESCED row-major from global (touched once), forms e = exp(logit*g),
// wave-reduces the row sum, writes out normalized once. No scattered
// global loads anywhere in the hot loop.
__global__ __launch_bounds__(512, 4) void score_kernel(
    const float* __restrict__ logits,
    const float* __restrict__ features,
    const _Float16* __restrict__ m16f,
    const float* __restrict__ pm2,
    const float* __restrict__ psh,
    const float* __restrict__ pli,
    const float* __restrict__ pis,
    float* __restrict__ out)
{
    __shared__ float se[16][SE_STRIDE];                  // 64256 B: g values

    const int lane = threadIdx.x & 63;
    const int wave = threadIdx.x >> 6;
    const int q    = lane >> 4;                          // class sub-group (4 classes)
    const int mr   = lane & 15;                          // row within block's 16-row tile
    const int row  = blockIdx.x * 16 + mr;

    const half8* mbase = (const half8*)m16f + (size_t)(wave * 8) * 8 * 64 + lane;

    // ---- prefetch tile 0 A-fragments early ----
    half8 a[8];
    #pragma unroll
    for (int kk = 0; kk < 8; ++kk)
        a[kk] = mbase[kk * 64];

    // ---- B fragments (features for this lane's row) + exact-fp32 f2 ----
    half8 bfrag[8];
    float f2 = 0.f;
    const float* fb = features + (size_t)row * NF;
    #pragma unroll
    for (int kk = 0; kk < 8; ++kk) {
        const float4* p = (const float4*)(fb + kk * 32 + q * 8);
        const float4 lo = p[0], hi = p[1];
        f2 += lo.x*lo.x + lo.y*lo.y + lo.z*lo.z + lo.w*lo.w
            + hi.x*hi.x + hi.y*hi.y + hi.z*hi.z + hi.w*hi.w;
        half8 b;
        b[0]=(_Float16)lo.x; b[1]=(_Float16)lo.y; b[2]=(_Float16)lo.z; b[3]=(_Float16)lo.w;
        b[4]=(_Float16)hi.x; b[5]=(_Float16)hi.y; b[6]=(_Float16)hi.z; b[7]=(_Float16)hi.w;
        bfrag[kk] = b;
    }
    f2 += __shfl_xor(f2, 16, 64);                        // sum the 4 q-chunks (same row)
    f2 += __shfl_xor(f2, 32, 64);

    const float LOG2E = 1.44269504088896340736f;

    #pragma unroll
    for (int t = 0; t < 8; ++t) {
        const int gt   = wave * 8 + t;                   // global class tile 0..63
        const int cb   = gt * 16 + q * 4;
        const bool cvg = (cb <= NC - 4);                 // all-4-or-none lane validity
        const int cbc  = cvg ? cb : (NC - 4);            // clamped, 16B aligned

        // ---- MFMA on prefetched tile t ----
        f32x4 acc = {0.f, 0.f, 0.f, 0.f};
        #pragma unroll
        for (int kk = 0; kk < 8; ++kk)
            acc = __builtin_amdgcn_mfma_f32_16x16x32_f16(a[kk], bfrag[kk], acc, 0, 0, 0);

        // ---- issue tile t+1 means loads; Weibull below covers L2 latency ----
        if (t < 7) {
            #pragma unroll
            for (int kk = 0; kk < 8; ++kk)
                a[kk] = mbase[(size_t)((t + 1) * 8 + kk) * 64];
        }

        // ---- per-class params (16KB total, cache-hot broadcasts) ----
        const float4 m2v = *(const float4*)(pm2 + cbc);
        const float4 shv = *(const float4*)(psh + cbc);
        const float4 liv = *(const float4*)(pli + cbc);
        const float4 iv  = *(const float4*)(pis + cbc);

        const float* m2a = (const float*)&m2v;
        const float* sha = (const float*)&shv;
        const float* lia = (const float*)&liv;
        const float* iva = (const float*)&iv;

        f32x4 o;
        #pragma unroll
        for (int j = 0; j < 4; ++j) {
            float d2   = fmaxf(f2 + m2a[j] - 2.0f * acc[j], 1e-12f);
            float dist = sqrtf(d2);
            float xp   = dist * iva[j] - lia[j];         // (dist-loc)/scale
            float xs   = fmaxf(xp, 1e-30f);
            float tt   = exp2f(sha[j] * log2f(xs));      // xp^shape
            float w    = 1.0f - exp2f(-LOG2E * tt);      // weibull CDF
            w = (xp > 0.f) ? w : 0.f;
            float w2 = w * w, w4 = w2 * w2, w8 = w4 * w4;
            o[j] = 1.0f - w8 * w2;                       // g = 1 - w^10
        }

        if (cvg)
            *(f32x4*)&se[mr][cb] = o;                    // g row-buffer in LDS
    }

    __syncthreads();                                     // all g writes visible

    // ---- phase 2: per wave, 2 complete rows; logits read ONCE, coalesced ----
    #pragma unroll
    for (int rr = 0; rr < 2; ++rr) {
        const int r = wave * 2 + rr;
        const size_t grow = (size_t)(blockIdx.x * 16 + r);
        const float* lrow = logits + grow * NC;

        float4 ev[4];
        float psum = 0.f;
        #pragma unroll
        for (int i = 0; i < 4; ++i) {
            const int idx = i * 64 + lane;               // float4 index within row
            if (idx < 250) {
                const float4 g4 = *(const float4*)&se[r][idx * 4];
                const float4 l4 = *(const float4*)(lrow + idx * 4);
                float4 e4;
                e4.x = exp2f(LOG2E * (l4.x * g4.x));
                e4.y = exp2f(LOG2E * (l4.y * g4.y));
                e4.z = exp2f(LOG2E * (l4.z * g4.z));
                e4.w = exp2f(LOG2E * (l4.w * g4.w));
                ev[i] = e4;
                psum += (e4.x + e4.y) + (e4.z + e4.w);
            }
        }
        #pragma unroll
        for (int off = 1; off < 64; off <<= 1)
            psum += __shfl_xor(psum, off, 64);           // full row sum, all lanes
        const float inv = 1.0f / psum;

        float* orow = out + grow * NC;
        #pragma unroll
        for (int i = 0; i < 4; ++i) {
            const int idx = i * 64 + lane;
            if (idx < 250) {
                float4 v = ev[i];
                v.x *= inv; v.y *= inv; v.z *= inv; v.w *= inv;
                *(float4*)(orow + idx * 4) = v;
            }
        }
    }
}

extern "C" void kernel_launch(void* const* d_in, const int* in_sizes, int n_in,
                              void* d_out, int out_size, void* d_ws, size_t ws_size,
                              hipStream_t stream) {
    const float* logits    = (const float*)d_in[0];
    const float* features  = (const float*)d_in[1];
    const float* mean_vecs = (const float*)d_in[2];
    const float* wb_shape  = (const float*)d_in[3];
    const float* wb_loc    = (const float*)d_in[4];
    const float* wb_scale  = (const float*)d_in[5];
    float* out = (float*)d_out;

    // ws layout: m16f 524288 B | pm2 4096 | psh 4096 | pli 4096 | pis 4096
    _Float16* m16f = (_Float16*)d_ws;
    float* pm2 = (float*)((char*)d_ws + 524288);
    float* psh = (float*)((char*)d_ws + 524288 + 4096);
    float* pli = (float*)((char*)d_ws + 524288 + 8192);
    float* pis = (float*)((char*)d_ws + 524288 + 12288);

    prep_kernel<<<252, 256, 0, stream>>>(mean_vecs, wb_shape, wb_loc, wb_scale,
                                         m16f, pm2, psh, pli, pis);
    score_kernel<<<NB / 16, 512, 0, stream>>>(logits, features, m16f,
                                              pm2, psh, pli, pis, out);
}

// Round 5
// 163.091 us; speedup vs baseline: 1.1790x; 1.0475x over previous
//
#include <hip/hip_runtime.h>

#define NB 16384
#define NC 1000
#define NF 256
#define SE_STRIDE 1004   // floats per g-row in LDS (1000 + pad, 16B-aligned)

typedef _Float16 half8 __attribute__((ext_vector_type(8)));
typedef float f32x4 __attribute__((ext_vector_type(4)));

// ---- prep: fragment-ordered fp16 means + SoA per-class params ----
// m16f layout: [gt 0..63][kk 0..7][slot 0..63] half8 units where
//   slot s of (gt,kk) = means[min(gt*16+(s&15),999)][kk*32+(s>>4)*8 .. +8]
// Matches the mfma_f32_16x16x32_f16 A-operand lane layout exactly: score's
// per-(tile,kk) means load is ONE coalesced 1024B dwordx4 per wave.
__global__ __launch_bounds__(256) void prep_kernel(
    const float* __restrict__ mean_vecs,
    const float* __restrict__ wb_shape,
    const float* __restrict__ wb_loc,
    const float* __restrict__ wb_scale,
    _Float16* __restrict__ m16f,
    float* __restrict__ pm2,
    float* __restrict__ psh,
    float* __restrict__ pli,
    float* __restrict__ pis)
{
    const int lane = threadIdx.x & 63;
    const int W = blockIdx.x * 4 + (threadIdx.x >> 6);   // grid=252 -> W in [0,1008)

    if (W < 512) {                                       // fragment-order means
        const int gt = W >> 3, kk = W & 7;
        int cls = gt * 16 + (lane & 15);
        if (cls > NC - 1) cls = NC - 1;                  // clamp tail slots
        const float* src = mean_vecs + (size_t)cls * NF + kk * 32 + (lane >> 4) * 8;
        const float4 lo = *(const float4*)src;
        const float4 hi = *(const float4*)(src + 4);
        half8 h;
        h[0]=(_Float16)lo.x; h[1]=(_Float16)lo.y; h[2]=(_Float16)lo.z; h[3]=(_Float16)lo.w;
        h[4]=(_Float16)hi.x; h[5]=(_Float16)hi.y; h[6]=(_Float16)hi.z; h[7]=(_Float16)hi.w;
        *((half8*)m16f + (size_t)W * 64 + lane) = h;     // coalesced 1024B per wave
    }
    if (W < NC) {                                        // per-class params, exact fp32 m2
        const float4 v = *((const float4*)(mean_vecs + (size_t)W * NF) + lane);
        float s = v.x*v.x + v.y*v.y + v.z*v.z + v.w*v.w;
        #pragma unroll
        for (int off = 1; off < 64; off <<= 1) s += __shfl_xor(s, off, 64);
        if (lane == 0) {
            const float isc = 1.0f / wb_scale[W];
            pm2[W] = s;
            psh[W] = wb_shape[W];
            pli[W] = wb_loc[W] * isc;                    // loc/scale
            pis[W] = isc;
        }
    }
}

// ---- single-pass score: 16 rows x all 1000 classes per block ----
// Params live in LDS (staged once per block), so the main loop's ONLY VMEM
// stream is the 1-tile-deep means prefetch -- no vmcnt serialization of
// params against the prefetch. g = 1 - w^10 goes to a 64KB LDS buffer.
// Phase-2 logits are prefetched before the barrier (HBM latency hides under
// the barrier wait); each wave then normalizes 2 full rows and writes once.
__global__ __launch_bounds__(512, 4) void score_kernel(
    const float* __restrict__ logits,
    const float* __restrict__ features,
    const _Float16* __restrict__ m16f,
    const float* __restrict__ pm2,
    const float* __restrict__ psh,
    const float* __restrict__ pli,
    const float* __restrict__ pis,
    float* __restrict__ out)
{
    __shared__ float se[16][SE_STRIDE];                  // 64256 B: g values
    __shared__ float sp[4][1024];                        // 16384 B: m2/sh/li/is

    const int lane = threadIdx.x & 63;
    const int wave = threadIdx.x >> 6;
    const int q    = lane >> 4;                          // class sub-group (4 classes)
    const int mr   = lane & 15;                          // row within block's 16-row tile
    const int row  = blockIdx.x * 16 + mr;

    // ---- stage params to LDS (once per block, 16KB, L2-hot) ----
    {
        const int t = threadIdx.x;
        if (t < 256) {
            ((float4*)&sp[0][0])[t] = ((const float4*)pm2)[t];
            ((float4*)&sp[2][0])[t] = ((const float4*)pli)[t];
        } else {
            const int u = t - 256;
            ((float4*)&sp[1][0])[u] = ((const float4*)psh)[u];
            ((float4*)&sp[3][0])[u] = ((const float4*)pis)[u];
        }
    }

    const half8* mbase = (const half8*)m16f + (size_t)(wave * 8) * 8 * 64 + lane;

    // ---- prefetch tile 0 A-fragments early ----
    half8 a[8];
    #pragma unroll
    for (int kk = 0; kk < 8; ++kk)
        a[kk] = mbase[kk * 64];

    // ---- B fragments (features for this lane's row) + exact-fp32 f2 ----
    half8 bfrag[8];
    float f2 = 0.f;
    const float* fb = features + (size_t)row * NF;
    #pragma unroll
    for (int kk = 0; kk < 8; ++kk) {
        const float4* p = (const float4*)(fb + kk * 32 + q * 8);
        const float4 lo = p[0], hi = p[1];
        f2 += lo.x*lo.x + lo.y*lo.y + lo.z*lo.z + lo.w*lo.w
            + hi.x*hi.x + hi.y*hi.y + hi.z*hi.z + hi.w*hi.w;
        half8 b;
        b[0]=(_Float16)lo.x; b[1]=(_Float16)lo.y; b[2]=(_Float16)lo.z; b[3]=(_Float16)lo.w;
        b[4]=(_Float16)hi.x; b[5]=(_Float16)hi.y; b[6]=(_Float16)hi.z; b[7]=(_Float16)hi.w;
        bfrag[kk] = b;
    }
    f2 += __shfl_xor(f2, 16, 64);                        // sum the 4 q-chunks (same row)
    f2 += __shfl_xor(f2, 32, 64);

    __syncthreads();                                     // sp staged

    const float LOG2E = 1.44269504088896340736f;

    #pragma unroll
    for (int t = 0; t < 8; ++t) {
        const int gt   = wave * 8 + t;                   // global class tile 0..63
        const int cb   = gt * 16 + q * 4;
        const bool cvg = (cb <= NC - 4);                 // all-4-or-none lane validity
        const int cbc  = cvg ? cb : (NC - 4);            // clamped, 16B aligned

        // ---- MFMA on prefetched tile t: two independent 4-chains ----
        f32x4 acc0 = {0.f, 0.f, 0.f, 0.f};
        f32x4 acc1 = {0.f, 0.f, 0.f, 0.f};
        #pragma unroll
        for (int kk = 0; kk < 4; ++kk) {
            acc0 = __builtin_amdgcn_mfma_f32_16x16x32_f16(a[kk],     bfrag[kk],     acc0, 0, 0, 0);
            acc1 = __builtin_amdgcn_mfma_f32_16x16x32_f16(a[kk + 4], bfrag[kk + 4], acc1, 0, 0, 0);
        }

        // ---- issue tile t+1 means loads (sole VMEM stream in the loop) ----
        if (t < 7) {
            #pragma unroll
            for (int kk = 0; kk < 8; ++kk)
                a[kk] = mbase[(size_t)((t + 1) * 8 + kk) * 64];
        }

        // ---- per-class params from LDS (broadcast within q-group) ----
        const f32x4 m2v = *(const f32x4*)&sp[0][cbc];
        const f32x4 shv = *(const f32x4*)&sp[1][cbc];
        const f32x4 liv = *(const f32x4*)&sp[2][cbc];
        const f32x4 iv  = *(const f32x4*)&sp[3][cbc];

        f32x4 o;
        #pragma unroll
        for (int j = 0; j < 4; ++j) {
            float av   = acc0[j] + acc1[j];
            float d2   = fmaxf(f2 + m2v[j] - 2.0f * av, 1e-12f);
            float dist = sqrtf(d2);
            float xp   = dist * iv[j] - liv[j];          // (dist-loc)/scale
            float xs   = fmaxf(xp, 1e-30f);
            float tt   = exp2f(shv[j] * log2f(xs));      // xp^shape
            float w    = 1.0f - exp2f(-LOG2E * tt);      // weibull CDF
            w = (xp > 0.f) ? w : 0.f;
            float w2 = w * w, w4 = w2 * w2, w8 = w4 * w4;
            o[j] = 1.0f - w8 * w2;                       // g = 1 - w^10
        }

        if (cvg)
            *(f32x4*)&se[mr][cb] = o;                    // g row-buffer in LDS
    }

    // ---- prefetch phase-2 logits BEFORE the barrier (HBM latency hides) ----
    float4 lgp[2][4];
    #pragma unroll
    for (int rr = 0; rr < 2; ++rr) {
        const size_t grow = (size_t)(blockIdx.x * 16 + wave * 2 + rr);
        const float* lrow = logits + grow * NC;
        #pragma unroll
        for (int i = 0; i < 4; ++i) {
            const int idx = i * 64 + lane;
            if (idx < 250) lgp[rr][i] = *(const float4*)(lrow + idx * 4);
        }
    }

    __syncthreads();                                     // all g writes visible

    // ---- phase 2: per wave, 2 complete rows; normalized write, once ----
    #pragma unroll
    for (int rr = 0; rr < 2; ++rr) {
        const int r = wave * 2 + rr;
        const size_t grow = (size_t)(blockIdx.x * 16 + r);

        float4 ev[4];
        float psum = 0.f;
        #pragma unroll
        for (int i = 0; i < 4; ++i) {
            const int idx = i * 64 + lane;               // float4 index within row
            if (idx < 250) {
                const float4 g4 = *(const float4*)&se[r][idx * 4];
                const float4 l4 = lgp[rr][i];
                float4 e4;
                e4.x = exp2f(LOG2E * (l4.x * g4.x));
                e4.y = exp2f(LOG2E * (l4.y * g4.y));
                e4.z = exp2f(LOG2E * (l4.z * g4.z));
                e4.w = exp2f(LOG2E * (l4.w * g4.w));
                ev[i] = e4;
                psum += (e4.x + e4.y) + (e4.z + e4.w);
            }
        }
        #pragma unroll
        for (int off = 1; off < 64; off <<= 1)
            psum += __shfl_xor(psum, off, 64);           // full row sum, all lanes
        const float inv = 1.0f / psum;

        float* orow = out + grow * NC;
        #pragma unroll
        for (int i = 0; i < 4; ++i) {
            const int idx = i * 64 + lane;
            if (idx < 250) {
                float4 v = ev[i];
                v.x *= inv; v.y *= inv; v.z *= inv; v.w *= inv;
                *(float4*)(orow + idx * 4) = v;
            }
        }
    }
}

extern "C" void kernel_launch(void* const* d_in, const int* in_sizes, int n_in,
                              void* d_out, int out_size, void* d_ws, size_t ws_size,
                              hipStream_t stream) {
    const float* logits    = (const float*)d_in[0];
    const float* features  = (const float*)d_in[1];
    const float* mean_vecs = (const float*)d_in[2];
    const float* wb_shape  = (const float*)d_in[3];
    const float* wb_loc    = (const float*)d_in[4];
    const float* wb_scale  = (const float*)d_in[5];
    float* out = (float*)d_out;

    // ws layout: m16f 524288 B | pm2 4096 | psh 4096 | pli 4096 | pis 4096
    _Float16* m16f = (_Float16*)d_ws;
    float* pm2 = (float*)((char*)d_ws + 524288);
    float* psh = (float*)((char*)d_ws + 524288 + 4096);
    float* pli = (float*)((char*)d_ws + 524288 + 8192);
    float* pis = (float*)((char*)d_ws + 524288 + 12288);

    prep_kernel<<<252, 256, 0, stream>>>(mean_vecs, wb_shape, wb_loc, wb_scale,
                                         m16f, pm2, psh, pli, pis);
    score_kernel<<<NB / 16, 512, 0, stream>>>(logits, features, m16f,
                                              pm2, psh, pli, pis, out);
}

// Round 7
// 161.422 us; speedup vs baseline: 1.1912x; 1.0103x over previous
//
#include <hip/hip_runtime.h>

#define NB 16384
#define NC 1000
#define NF 256
#define SE_STRIDE 1004   // halves per g-row in LDS: 2008B row stride, 8B-aligned,
                         // word-stride 502 (mod 32 = 22) -> 16 distinct banks over mr

typedef _Float16 half8 __attribute__((ext_vector_type(8)));
typedef _Float16 half4v __attribute__((ext_vector_type(4)));
typedef float f32x4 __attribute__((ext_vector_type(4)));

// ---- prep: fragment-ordered fp16 means + SoA per-class params ----
// m16f layout: [gt 0..63][kk 0..7][slot 0..63] half8 units where
//   slot s of (gt,kk) = means[min(gt*16+(s&15),999)][kk*32+(s>>4)*8 .. +8]
// Matches the mfma_f32_16x16x32_f16 A-operand lane layout exactly: score's
// per-(tile,kk) means load is ONE coalesced 1024B dwordx4 per wave.
__global__ __launch_bounds__(256) void prep_kernel(
    const float* __restrict__ mean_vecs,
    const float* __restrict__ wb_shape,
    const float* __restrict__ wb_loc,
    const float* __restrict__ wb_scale,
    _Float16* __restrict__ m16f,
    float* __restrict__ pm2,
    float* __restrict__ psh,
    float* __restrict__ pli,
    float* __restrict__ pis)
{
    const int lane = threadIdx.x & 63;
    const int W = blockIdx.x * 4 + (threadIdx.x >> 6);   // grid=252 -> W in [0,1008)

    if (W < 512) {                                       // fragment-order means
        const int gt = W >> 3, kk = W & 7;
        int cls = gt * 16 + (lane & 15);
        if (cls > NC - 1) cls = NC - 1;                  // clamp tail slots
        const float* src = mean_vecs + (size_t)cls * NF + kk * 32 + (lane >> 4) * 8;
        const float4 lo = *(const float4*)src;
        const float4 hi = *(const float4*)(src + 4);
        half8 h;
        h[0]=(_Float16)lo.x; h[1]=(_Float16)lo.y; h[2]=(_Float16)lo.z; h[3]=(_Float16)lo.w;
        h[4]=(_Float16)hi.x; h[5]=(_Float16)hi.y; h[6]=(_Float16)hi.z; h[7]=(_Float16)hi.w;
        *((half8*)m16f + (size_t)W * 64 + lane) = h;     // coalesced 1024B per wave
    }
    if (W < NC) {                                        // per-class params, exact fp32 m2
        const float4 v = *((const float4*)(mean_vecs + (size_t)W * NF) + lane);
        float s = v.x*v.x + v.y*v.y + v.z*v.z + v.w*v.w;
        #pragma unroll
        for (int off = 1; off < 64; off <<= 1) s += __shfl_xor(s, off, 64);
        if (lane == 0) {
            const float isc = 1.0f / wb_scale[W];
            pm2[W] = s;
            psh[W] = wb_shape[W];
            pli[W] = wb_loc[W] * isc;                    // loc/scale
            pis[W] = isc;
        }
    }
}

// ---- single-pass score: 16 rows x all 1000 classes per block ----
// g = 1 - w^10 stored as FP16 in LDS (32.1KB) + fp32 params (16KB) ->
// 48.5KB total -> 3 blocks/CU (24 waves, vs 2 blocks before). Transcendentals
// are raw HW ops (v_sqrt/v_log/v_exp, single-instr, ~1ulp) instead of libm
// wrappers -- roughly halves main-loop VALU issue. Main loop's only VMEM is
// the 1-tile-deep means prefetch. Phase-2 logits prefetched (and pre-scaled
// by LOG2E) before the barrier; each wave normalizes 2 full rows, writes once.
__global__ __launch_bounds__(512, 4) void score_kernel(
    const float* __restrict__ logits,
    const float* __restrict__ features,
    const _Float16* __restrict__ m16f,
    const float* __restrict__ pm2,
    const float* __restrict__ psh,
    const float* __restrict__ pli,
    const float* __restrict__ pis,
    float* __restrict__ out)
{
    __shared__ _Float16 se[16][SE_STRIDE];               // 32128 B: g values (fp16)
    __shared__ float sp[4][1024];                        // 16384 B: m2/sh/li/is

    const int lane = threadIdx.x & 63;
    const int wave = threadIdx.x >> 6;
    const int q    = lane >> 4;                          // class sub-group (4 classes)
    const int mr   = lane & 15;                          // row within block's 16-row tile
    const int row  = blockIdx.x * 16 + mr;

    // ---- stage params to LDS (once per block, 16KB, L2-hot) ----
    {
        const int t = threadIdx.x;
        if (t < 256) {
            ((float4*)&sp[0][0])[t] = ((const float4*)pm2)[t];
            ((float4*)&sp[2][0])[t] = ((const float4*)pli)[t];
        } else {
            const int u = t - 256;
            ((float4*)&sp[1][0])[u] = ((const float4*)psh)[u];
            ((float4*)&sp[3][0])[u] = ((const float4*)pis)[u];
        }
    }

    const half8* mbase = (const half8*)m16f + (size_t)(wave * 8) * 8 * 64 + lane;

    // ---- prefetch tile 0 A-fragments early ----
    half8 a[8];
    #pragma unroll
    for (int kk = 0; kk < 8; ++kk)
        a[kk] = mbase[kk * 64];

    // ---- B fragments (features for this lane's row) + exact-fp32 f2 ----
    half8 bfrag[8];
    float f2 = 0.f;
    const float* fb = features + (size_t)row * NF;
    #pragma unroll
    for (int kk = 0; kk < 8; ++kk) {
        const float4* p = (const float4*)(fb + kk * 32 + q * 8);
        const float4 lo = p[0], hi = p[1];
        f2 += lo.x*lo.x + lo.y*lo.y + lo.z*lo.z + lo.w*lo.w
            + hi.x*hi.x + hi.y*hi.y + hi.z*hi.z + hi.w*hi.w;
        half8 b;
        b[0]=(_Float16)lo.x; b[1]=(_Float16)lo.y; b[2]=(_Float16)lo.z; b[3]=(_Float16)lo.w;
        b[4]=(_Float16)hi.x; b[5]=(_Float16)hi.y; b[6]=(_Float16)hi.z; b[7]=(_Float16)hi.w;
        bfrag[kk] = b;
    }
    f2 += __shfl_xor(f2, 16, 64);                        // sum the 4 q-chunks (same row)
    f2 += __shfl_xor(f2, 32, 64);

    __syncthreads();                                     // sp staged

    const float LOG2E = 1.44269504088896340736f;
    const float NL2E  = -1.44269504088896340736f;

    #pragma unroll
    for (int t = 0; t < 8; ++t) {
        const int gt   = wave * 8 + t;                   // global class tile 0..63
        const int cb   = gt * 16 + q * 4;
        const bool cvg = (cb <= NC - 4);                 // all-4-or-none lane validity
        const int cbc  = cvg ? cb : (NC - 4);            // clamped, 16B aligned

        // ---- MFMA on prefetched tile t: two independent 4-chains ----
        f32x4 acc0 = {0.f, 0.f, 0.f, 0.f};
        f32x4 acc1 = {0.f, 0.f, 0.f, 0.f};
        #pragma unroll
        for (int kk = 0; kk < 4; ++kk) {
            acc0 = __builtin_amdgcn_mfma_f32_16x16x32_f16(a[kk],     bfrag[kk],     acc0, 0, 0, 0);
            acc1 = __builtin_amdgcn_mfma_f32_16x16x32_f16(a[kk + 4], bfrag[kk + 4], acc1, 0, 0, 0);
        }

        // ---- issue tile t+1 means loads (sole VMEM stream in the loop) ----
        if (t < 7) {
            #pragma unroll
            for (int kk = 0; kk < 8; ++kk)
                a[kk] = mbase[(size_t)((t + 1) * 8 + kk) * 64];
        }

        // ---- per-class params from LDS (broadcast within q-group) ----
        const f32x4 m2v = *(const f32x4*)&sp[0][cbc];
        const f32x4 shv = *(const f32x4*)&sp[1][cbc];
        const f32x4 liv = *(const f32x4*)&sp[2][cbc];
        const f32x4 iv  = *(const f32x4*)&sp[3][cbc];

        half4v oh;
        #pragma unroll
        for (int j = 0; j < 4; ++j) {
            float av   = acc0[j] + acc1[j];
            float d2   = fmaxf(f2 + m2v[j] - 2.0f * av, 1e-12f);
            float dist = __builtin_amdgcn_sqrtf(d2);                 // v_sqrt_f32
            float xp   = dist * iv[j] - liv[j];                      // (dist-loc)/scale
            float xs   = fmaxf(xp, 1e-30f);
            float tt   = __builtin_amdgcn_exp2f(
                             shv[j] * __builtin_amdgcn_logf(xs));    // xp^shape
            float w    = 1.0f - __builtin_amdgcn_exp2f(NL2E * tt);   // weibull CDF
            w = (xp > 0.f) ? w : 0.f;
            float w2 = w * w, w4 = w2 * w2, w8 = w4 * w4;
            oh[j] = (_Float16)(1.0f - w8 * w2);                      // g = 1 - w^10
        }

        if (cvg)
            *(half4v*)&se[mr][cb] = oh;                  // g row-buffer in LDS (8B store)
    }

    // ---- prefetch phase-2 logits BEFORE the barrier (HBM latency hides);
    //      pre-scale by LOG2E so phase 2 is one mul + one v_exp per element ----
    float4 lgp[2][4];
    #pragma unroll
    for (int rr = 0; rr < 2; ++rr) {
        const size_t grow = (size_t)(blockIdx.x * 16 + wave * 2 + rr);
        const float* lrow = logits + grow * NC;
        #pragma unroll
        for (int i = 0; i < 4; ++i) {
            const int idx = i * 64 + lane;
            if (idx < 250) {
                float4 l4 = *(const float4*)(lrow + idx * 4);
                l4.x *= LOG2E; l4.y *= LOG2E; l4.z *= LOG2E; l4.w *= LOG2E;
                lgp[rr][i] = l4;
            }
        }
    }

    __syncthreads();                                     // all g writes visible

    // ---- phase 2: per wave, 2 complete rows; normalized write, once ----
    #pragma unroll
    for (int rr = 0; rr < 2; ++rr) {
        const int r = wave * 2 + rr;
        const size_t grow = (size_t)(blockIdx.x * 16 + r);

        float4 ev[4];
        float psum = 0.f;
        #pragma unroll
        for (int i = 0; i < 4; ++i) {
            const int idx = i * 64 + lane;               // half4 index within row
            if (idx < 250) {
                const half4v g4 = *(const half4v*)&se[r][idx * 4];
                const float4 l4 = lgp[rr][i];
                float4 e4;
                e4.x = __builtin_amdgcn_exp2f(l4.x * (float)g4[0]);
                e4.y = __builtin_amdgcn_exp2f(l4.y * (float)g4[1]);
                e4.z = __builtin_amdgcn_exp2f(l4.z * (float)g4[2]);
                e4.w = __builtin_amdgcn_exp2f(l4.w * (float)g4[3]);
                ev[i] = e4;
                psum += (e4.x + e4.y) + (e4.z + e4.w);
            }
        }
        #pragma unroll
        for (int off = 1; off < 64; off <<= 1)
            psum += __shfl_xor(psum, off, 64);           // full row sum, all lanes
        const float inv = 1.0f / psum;

        float* orow = out + grow * NC;
        #pragma unroll
        for (int i = 0; i < 4; ++i) {
            const int idx = i * 64 + lane;
            if (idx < 250) {
                float4 v = ev[i];
                v.x *= inv; v.y *= inv; v.z *= inv; v.w *= inv;
                *(float4*)(orow + idx * 4) = v;
            }
        }
    }
}

extern "C" void kernel_launch(void* const* d_in, const int* in_sizes, int n_in,
                              void* d_out, int out_size, void* d_ws, size_t ws_size,
                              hipStream_t stream) {
    const float* logits    = (const float*)d_in[0];
    const float* features  = (const float*)d_in[1];
    const float* mean_vecs = (const float*)d_in[2];
    const float* wb_shape  = (const float*)d_in[3];
    const float* wb_loc    = (const float*)d_in[4];
    const float* wb_scale  = (const float*)d_in[5];
    float* out = (float*)d_out;

    // ws layout: m16f 524288 B | pm2 4096 | psh 4096 | pli 4096 | pis 4096
    _Float16* m16f = (_Float16*)d_ws;
    float* pm2 = (float*)((char*)d_ws + 524288);
    float* psh = (float*)((char*)d_ws + 524288 + 4096);
    float* pli = (float*)((char*)d_ws + 524288 + 8192);
    float* pis = (float*)((char*)d_ws + 524288 + 12288);

    prep_kernel<<<252, 256, 0, stream>>>(mean_vecs, wb_shape, wb_loc, wb_scale,
                                         m16f, pm2, psh, pli, pis);
    score_kernel<<<NB / 16, 512, 0, stream>>>(logits, features, m16f,
                                              pm2, psh, pli, pis, out);
}